// Round 1
// baseline (429.434 us; speedup 1.0000x reference)
//
#include <hip/hip_runtime.h>

using f32x4 = __attribute__((ext_vector_type(4))) float;
using s16x8 = __attribute__((ext_vector_type(8))) short;
using u16   = unsigned short;
using u32   = unsigned int;
using u16x4 = __attribute__((ext_vector_type(4))) unsigned short;

#define S_LEN 4096
#define NH 8
#define DM 512
#define MROWS 8192  // B*S

// ---------- helpers ----------
static __device__ __forceinline__ u16 f2bf(float f) {
  u32 x = __builtin_bit_cast(u32, f);
  return (u16)((x + 0x7FFFu + ((x >> 16) & 1u)) >> 16);
}

typedef __attribute__((address_space(3))) void lds_void_t;
typedef const __attribute__((address_space(1))) void gbl_void_t;

static __device__ __forceinline__ void gload16(const void* g, void* l) {
  __builtin_amdgcn_global_load_lds((gbl_void_t*)g, (lds_void_t*)l, 16, 0, 0);
}

// read 16B MFMA fragment from a swizzled row-major [R][64]-bf16 LDS tile.
// logical (row, chunk c in 0..7) -> physical chunk c ^ (row&7)
static __device__ __forceinline__ s16x8 lds_frag(const u16* base, int row, int c) {
  return *(const s16x8*)(base + row * 64 + ((c ^ (row & 7)) << 3));
}

// ---------- fp32 -> bf16 conversion ----------
__global__ void cvt_kernel(const float* __restrict__ in, u16* __restrict__ out, int n4) {
  int i = blockIdx.x * blockDim.x + threadIdx.x;
  if (i < n4) {
    float4 v = ((const float4*)in)[i];
    u16x4 o;
    o.x = f2bf(v.x); o.y = f2bf(v.y); o.z = f2bf(v.z); o.w = f2bf(v.w);
    ((u16x4*)out)[i] = o;
  }
}

// ---------- NT bf16 GEMM: C[m][n] = sum_k A[m][k]*B[n][k] ----------
// A [8192][512], B [512][512], 128x128 tile, BK=64, 256 thr / 4 waves (2x2 of 64x64)
// MODE 0: out bf16 [B][H][S][64]   (Q,K projections)
// MODE 1: out bf16 [B][H][64][S]   (V projection, transposed)
// MODE 2: out fp32 [8192][512]     (final)
template <int MODE>
__global__ __launch_bounds__(256) void gemm128(const u16* __restrict__ A,
                                               const u16* __restrict__ Bw,
                                               void* __restrict__ out) {
  __shared__ u16 As[128 * 64];
  __shared__ u16 Bs[128 * 64];
  const int tid = threadIdx.x;
  const int l = tid & 63, w = tid >> 6;
  const int g = l >> 4, r16 = l & 15;
  const int srow = l >> 3, p = l & 7;
  const int m0 = blockIdx.y * 128, n0 = blockIdx.x * 128;
  const int wr = w >> 1, wc = w & 1;

  f32x4 acc[4][4];
#pragma unroll
  for (int mi = 0; mi < 4; ++mi)
#pragma unroll
    for (int ni = 0; ni < 4; ++ni) acc[mi][ni] = (f32x4){0.f, 0.f, 0.f, 0.f};

  for (int kt = 0; kt < 8; ++kt) {
    const int k0 = kt * 64;
#pragma unroll
    for (int s = 0; s < 4; ++s) {
      const int seg = w * 4 + s;
      const int r = seg * 8 + srow;
      const int c = p ^ (r & 7);
      gload16(A + (size_t)(m0 + r) * DM + k0 + c * 8, &As[seg * 512]);
      gload16(Bw + (size_t)(n0 + r) * DM + k0 + c * 8, &Bs[seg * 512]);
    }
    __syncthreads();
    const u16* Ab = &As[wr * 64 * 64];
    const u16* Bb = &Bs[wc * 64 * 64];
#pragma unroll
    for (int kk = 0; kk < 2; ++kk) {
      s16x8 af[4], bf[4];
#pragma unroll
      for (int mi = 0; mi < 4; ++mi) af[mi] = lds_frag(Ab, mi * 16 + r16, kk * 4 + g);
#pragma unroll
      for (int ni = 0; ni < 4; ++ni) bf[ni] = lds_frag(Bb, ni * 16 + r16, kk * 4 + g);
#pragma unroll
      for (int mi = 0; mi < 4; ++mi)
#pragma unroll
        for (int ni = 0; ni < 4; ++ni)
          acc[mi][ni] = __builtin_amdgcn_mfma_f32_16x16x32_bf16(af[mi], bf[ni], acc[mi][ni], 0, 0, 0);
    }
    __syncthreads();
  }

#pragma unroll
  for (int mi = 0; mi < 4; ++mi)
#pragma unroll
    for (int ni = 0; ni < 4; ++ni) {
      const int mbase = m0 + wr * 64 + mi * 16 + g * 4;
      const int n = n0 + wc * 64 + ni * 16 + r16;
#pragma unroll
      for (int reg = 0; reg < 4; ++reg) {
        const int m = mbase + reg;
        const float v = acc[mi][ni][reg];
        if (MODE == 2) {
          ((float*)out)[(size_t)m * DM + n] = v;
        } else {
          const int b = m >> 12, s = m & 4095;
          const int h = n >> 6, d = n & 63;
          if (MODE == 0)
            ((u16*)out)[((size_t)(b * NH + h) * S_LEN + s) * 64 + d] = f2bf(v);
          else
            ((u16*)out)[((size_t)(b * NH + h) * 64 + d) * S_LEN + s] = f2bf(v);
        }
      }
    }
}

// ---------- causal flash attention ----------
// Qp,Kp bf16 [B][H][S][64]; VTp bf16 [B][H][64][S]; out bf16 [B*S][512]
// grid (S/64, B*H), 256 thr / 4 waves, wave w owns q-rows [q0+16w, q0+16w+16)
__global__ __launch_bounds__(256) void attn64(const u16* __restrict__ Qp,
                                              const u16* __restrict__ Kp,
                                              const u16* __restrict__ VTp,
                                              u16* __restrict__ Aout) {
  __shared__ u16 Kl[64 * 64];
  __shared__ u16 Vl[64 * 64];
  __shared__ u16 Pl[4][16 * 64];
  const int bh = blockIdx.y, qi = blockIdx.x, q0 = qi * 64;
  const int tid = threadIdx.x, l = tid & 63, w = tid >> 6;
  const int g = l >> 4, r16 = l & 15;
  const int srow = l >> 3, p = l & 7;

  const u16* qrow = Qp + ((size_t)bh * S_LEN + q0 + w * 16 + r16) * 64;
  const s16x8 aq0 = *(const s16x8*)(qrow + 8 * g);
  const s16x8 aq1 = *(const s16x8*)(qrow + 32 + 8 * g);

  f32x4 oacc[4];
#pragma unroll
  for (int ni = 0; ni < 4; ++ni) oacc[ni] = (f32x4){0.f, 0.f, 0.f, 0.f};
  float mrow[4] = {-1e30f, -1e30f, -1e30f, -1e30f};
  float lrow[4] = {0.f, 0.f, 0.f, 0.f};

  const u16* Kbase = Kp + (size_t)bh * S_LEN * 64;
  const u16* Vbase = VTp + (size_t)bh * 64 * S_LEN;

  for (int j = 0; j <= qi; ++j) {
#pragma unroll
    for (int s = 0; s < 4; ++s) {
      const int seg = w * 4 + s;
      const int r = seg * 8 + srow;
      const int c = p ^ (r & 7);
      gload16(Kbase + (size_t)(j * 64 + r) * 64 + c * 8, &Kl[seg * 512]);
      gload16(Vbase + (size_t)r * S_LEN + j * 64 + c * 8, &Vl[seg * 512]);
    }
    __syncthreads();

    const bool diag = (j == qi);
    const int cmax = diag ? w : 3;
    f32x4 sv[4];
#pragma unroll
    for (int ci = 0; ci < 4; ++ci) {
      if (ci <= cmax) {
        s16x8 bk0 = lds_frag(Kl, ci * 16 + r16, g);
        s16x8 bk1 = lds_frag(Kl, ci * 16 + r16, 4 + g);
        f32x4 t = (f32x4){0.f, 0.f, 0.f, 0.f};
        t = __builtin_amdgcn_mfma_f32_16x16x32_bf16(aq0, bk0, t, 0, 0, 0);
        t = __builtin_amdgcn_mfma_f32_16x16x32_bf16(aq1, bk1, t, 0, 0, 0);
        sv[ci] = t;
      }
    }

    float tmax[4] = {-1e30f, -1e30f, -1e30f, -1e30f};
#pragma unroll
    for (int ci = 0; ci < 4; ++ci) {
      if (ci <= cmax) {
#pragma unroll
        for (int reg = 0; reg < 4; ++reg) {
          float x = sv[ci][reg] * 0.125f;
          if (diag) {
            const int row = w * 16 + g * 4 + reg;
            const int col = ci * 16 + r16;
            if (col > row) x = -1e30f;
          }
          sv[ci][reg] = x;
          tmax[reg] = fmaxf(tmax[reg], x);
        }
      }
    }
#pragma unroll
    for (int d = 1; d < 16; d <<= 1)
#pragma unroll
      for (int reg = 0; reg < 4; ++reg) tmax[reg] = fmaxf(tmax[reg], __shfl_xor(tmax[reg], d));

    float mnew[4], fac[4], rsum[4] = {0.f, 0.f, 0.f, 0.f};
#pragma unroll
    for (int reg = 0; reg < 4; ++reg) {
      mnew[reg] = fmaxf(mrow[reg], tmax[reg]);
      fac[reg] = __expf(mrow[reg] - mnew[reg]);
      mrow[reg] = mnew[reg];
    }
#pragma unroll
    for (int ci = 0; ci < 4; ++ci) {
#pragma unroll
      for (int reg = 0; reg < 4; ++reg) {
        const float pv = (ci <= cmax) ? __expf(sv[ci][reg] - mnew[reg]) : 0.f;
        rsum[reg] += pv;
        const int row = g * 4 + reg;
        const int col = ci * 16 + r16;
        const int pc = (col >> 3) ^ (row & 7);
        Pl[w][row * 64 + pc * 8 + (col & 7)] = f2bf(pv);
      }
    }
#pragma unroll
    for (int d = 1; d < 16; d <<= 1)
#pragma unroll
      for (int reg = 0; reg < 4; ++reg) rsum[reg] += __shfl_xor(rsum[reg], d);
#pragma unroll
    for (int reg = 0; reg < 4; ++reg) lrow[reg] = lrow[reg] * fac[reg] + rsum[reg];
#pragma unroll
    for (int ni = 0; ni < 4; ++ni)
#pragma unroll
      for (int reg = 0; reg < 4; ++reg) oacc[ni][reg] *= fac[reg];

#pragma unroll
    for (int ni = 0; ni < 4; ++ni)
#pragma unroll
      for (int kk = 0; kk < 2; ++kk) {
        s16x8 pa = lds_frag(Pl[w], r16, kk * 4 + g);
        s16x8 bv = lds_frag(Vl, ni * 16 + r16, kk * 4 + g);
        oacc[ni] = __builtin_amdgcn_mfma_f32_16x16x32_bf16(pa, bv, oacc[ni], 0, 0, 0);
      }
    __syncthreads();
  }

  const int b = bh >> 3, h = bh & 7;
#pragma unroll
  for (int ni = 0; ni < 4; ++ni)
#pragma unroll
    for (int reg = 0; reg < 4; ++reg) {
      const int s = q0 + w * 16 + g * 4 + reg;
      const int d = ni * 16 + r16;
      Aout[((size_t)b * S_LEN + s) * DM + h * 64 + d] = f2bf(oacc[ni][reg] / lrow[reg]);
    }
}

// ---------- launch ----------
extern "C" void kernel_launch(void* const* d_in, const int* in_sizes, int n_in,
                              void* d_out, int out_size, void* d_ws, size_t ws_size,
                              hipStream_t stream) {
  const float* q  = (const float*)d_in[0];
  const float* k  = (const float*)d_in[1];
  const float* v  = (const float*)d_in[2];
  const float* wq = (const float*)d_in[3];
  const float* wk = (const float*)d_in[4];
  const float* wv = (const float*)d_in[5];
  const float* wo = (const float*)d_in[6];

  char* ws = (char*)d_ws;
  u16* Xq  = (u16*)(ws + 0);
  u16* Xk  = (u16*)(ws + 8388608);
  u16* Xv  = (u16*)(ws + 16777216);
  u16* Wq  = (u16*)(ws + 25165824);
  u16* Wk  = (u16*)(ws + 25690112);
  u16* Wv  = (u16*)(ws + 26214400);
  u16* Wo  = (u16*)(ws + 26738688);
  u16* Qp  = (u16*)(ws + 27262976);
  u16* Kp  = (u16*)(ws + 35651584);
  u16* VTp = (u16*)(ws + 44040192);
  u16* Att = (u16*)(ws + 52428800);

  const int n4_big = (MROWS * DM) / 4;   // 1048576
  const int n4_w   = (DM * DM) / 4;      // 65536
  cvt_kernel<<<dim3(n4_big / 256), dim3(256), 0, stream>>>(q, Xq, n4_big);
  cvt_kernel<<<dim3(n4_big / 256), dim3(256), 0, stream>>>(k, Xk, n4_big);
  cvt_kernel<<<dim3(n4_big / 256), dim3(256), 0, stream>>>(v, Xv, n4_big);
  cvt_kernel<<<dim3(n4_w / 256), dim3(256), 0, stream>>>(wq, Wq, n4_w);
  cvt_kernel<<<dim3(n4_w / 256), dim3(256), 0, stream>>>(wk, Wk, n4_w);
  cvt_kernel<<<dim3(n4_w / 256), dim3(256), 0, stream>>>(wv, Wv, n4_w);
  cvt_kernel<<<dim3(n4_w / 256), dim3(256), 0, stream>>>(wo, Wo, n4_w);

  dim3 ggrid(DM / 128, MROWS / 128);  // (4, 64)
  gemm128<0><<<ggrid, dim3(256), 0, stream>>>(Xq, Wq, (void*)Qp);
  gemm128<0><<<ggrid, dim3(256), 0, stream>>>(Xk, Wk, (void*)Kp);
  gemm128<1><<<ggrid, dim3(256), 0, stream>>>(Xv, Wv, (void*)VTp);

  attn64<<<dim3(S_LEN / 64, 2 * NH), dim3(256), 0, stream>>>(Qp, Kp, VTp, Att);

  gemm128<2><<<ggrid, dim3(256), 0, stream>>>(Att, Wo, d_out);
}

// Round 2
// 273.304 us; speedup vs baseline: 1.5713x; 1.5713x over previous
//
#include <hip/hip_runtime.h>

using f32x4 = __attribute__((ext_vector_type(4))) float;
using s16x8 = __attribute__((ext_vector_type(8))) short;
using u16   = unsigned short;
using u32   = unsigned int;
using u16x4 = __attribute__((ext_vector_type(4))) unsigned short;

#define S_LEN 4096
#define NH 8
#define DM 512
#define MROWS 8192  // B*S

// deeper XOR swizzle: distinguishes rows 8 apart (bit3 folded into bit1)
#define SWZ(r) ((((r) & 7)) ^ ((((r) >> 2) & 2)))

// ---------- helpers ----------
static __device__ __forceinline__ u16 f2bf(float f) {
  u32 x = __builtin_bit_cast(u32, f);
  return (u16)((x + 0x7FFFu + ((x >> 16) & 1u)) >> 16);
}

static __device__ __forceinline__ float fexp2(float x) {
#if __has_builtin(__builtin_amdgcn_exp2f)
  return __builtin_amdgcn_exp2f(x);
#else
  return exp2f(x);
#endif
}

static __device__ __forceinline__ float frcp(float x) {
#if __has_builtin(__builtin_amdgcn_rcpf)
  return __builtin_amdgcn_rcpf(x);
#else
  return 1.0f / x;
#endif
}

// max over 16 consecutive lanes via DPP (VALU pipe, no LDS traffic)
static __device__ __forceinline__ float dppmax16(float x) {
  int v;
  v = __builtin_amdgcn_update_dpp(0, __builtin_bit_cast(int, x), 0xB1, 0xF, 0xF, true);  // quad xor1
  x = fmaxf(x, __builtin_bit_cast(float, v));
  v = __builtin_amdgcn_update_dpp(0, __builtin_bit_cast(int, x), 0x4E, 0xF, 0xF, true);  // quad xor2
  x = fmaxf(x, __builtin_bit_cast(float, v));
  v = __builtin_amdgcn_update_dpp(0, __builtin_bit_cast(int, x), 0x141, 0xF, 0xF, true); // row_half_mirror
  x = fmaxf(x, __builtin_bit_cast(float, v));
  v = __builtin_amdgcn_update_dpp(0, __builtin_bit_cast(int, x), 0x140, 0xF, 0xF, true); // row_mirror
  x = fmaxf(x, __builtin_bit_cast(float, v));
  return x;
}

typedef __attribute__((address_space(3))) void lds_void_t;
typedef const __attribute__((address_space(1))) void gbl_void_t;

static __device__ __forceinline__ void gload16(const void* g, void* l) {
  __builtin_amdgcn_global_load_lds((gbl_void_t*)g, (lds_void_t*)l, 16, 0, 0);
}

// read 16B MFMA fragment from a swizzled row-major [R][64]-bf16 LDS tile
static __device__ __forceinline__ s16x8 lds_frag(const u16* base, int row, int c) {
  return *(const s16x8*)(base + row * 64 + ((c ^ SWZ(row)) << 3));
}

// ---------- fp32 -> bf16 conversion (merged) ----------
__global__ void cvt_qkv(const float* __restrict__ q, const float* __restrict__ k,
                        const float* __restrict__ v, u16* __restrict__ oq,
                        u16* __restrict__ ok, u16* __restrict__ ov) {
  const int z = blockIdx.y;
  const float* in = (z == 0) ? q : (z == 1) ? k : v;
  u16* out = (z == 0) ? oq : (z == 1) ? ok : ov;
  const int i = blockIdx.x * 256 + threadIdx.x;
  float4 t = ((const float4*)in)[i];
  u16x4 o;
  o.x = f2bf(t.x); o.y = f2bf(t.y); o.z = f2bf(t.z); o.w = f2bf(t.w);
  ((u16x4*)out)[i] = o;
}

// weight cvt; Wq carries the softmax scale folded in log2-domain: 0.125*log2(e)
__global__ void cvt_w(const float* __restrict__ wq, const float* __restrict__ wk,
                      const float* __restrict__ wv, const float* __restrict__ wo,
                      u16* __restrict__ Wq, u16* __restrict__ Wk,
                      u16* __restrict__ Wv, u16* __restrict__ Wo) {
  const int z = blockIdx.y;
  const float* in = (z == 0) ? wq : (z == 1) ? wk : (z == 2) ? wv : wo;
  u16* out = (z == 0) ? Wq : (z == 1) ? Wk : (z == 2) ? Wv : Wo;
  const float scale = (z == 0) ? 0.18033688011112042f : 1.0f;
  const int i = blockIdx.x * 256 + threadIdx.x;
  float4 t = ((const float4*)in)[i];
  u16x4 o;
  o.x = f2bf(t.x * scale); o.y = f2bf(t.y * scale);
  o.z = f2bf(t.z * scale); o.w = f2bf(t.w * scale);
  ((u16x4*)out)[i] = o;
}

// ---------- NT bf16 GEMM core: 128x64 tile, BK=64, double-buffered 2-phase ----------
// 256 thr / 4 waves; wave w owns rows [w*32, w*32+32) of the 128-row tile.
static __device__ __forceinline__ void gemm_core(const u16* __restrict__ A,
                                                 const u16* __restrict__ Bw,
                                                 int m0, int n0, int tid,
                                                 f32x4 (&acc)[2][4], u16* As, u16* Bs) {
  const int l = tid & 63, w = tid >> 6;
  const int g = l >> 4, r16 = l & 15;

  auto stage = [&](int buf, int kt) {
    const int k0 = kt * 64;
#pragma unroll
    for (int s = 0; s < 4; ++s) {  // A: 128 rows x 64 cols = 16KB
      const int idx = s * 256 + tid;
      const int r = idx >> 3;
      const int c = (idx & 7) ^ SWZ(r);
      gload16(A + (size_t)(m0 + r) * DM + k0 + c * 8, As + buf * 8192 + (s * 4 + w) * 512);
    }
#pragma unroll
    for (int s = 0; s < 2; ++s) {  // B: 64 rows = 8KB
      const int idx = s * 256 + tid;
      const int r = idx >> 3;
      const int c = (idx & 7) ^ SWZ(r);
      gload16(Bw + (size_t)(n0 + r) * DM + k0 + c * 8, Bs + buf * 4096 + (s * 4 + w) * 512);
    }
  };

  stage(0, 0);
  __syncthreads();
  for (int kt = 0; kt < 8; ++kt) {
    const int cur = kt & 1;
    if (kt < 7) stage(cur ^ 1, kt + 1);  // issue next-tile loads BEFORE compute
    const u16* Ab = As + cur * 8192 + w * 32 * 64;
    const u16* Bb = Bs + cur * 4096;
#pragma unroll
    for (int kk = 0; kk < 2; ++kk) {
      s16x8 a0 = lds_frag(Ab, r16, kk * 4 + g);
      s16x8 a1 = lds_frag(Ab, 16 + r16, kk * 4 + g);
#pragma unroll
      for (int ni = 0; ni < 4; ++ni) {
        s16x8 bf = lds_frag(Bb, ni * 16 + r16, kk * 4 + g);
        acc[0][ni] = __builtin_amdgcn_mfma_f32_16x16x32_bf16(a0, bf, acc[0][ni], 0, 0, 0);
        acc[1][ni] = __builtin_amdgcn_mfma_f32_16x16x32_bf16(a1, bf, acc[1][ni], 0, 0, 0);
      }
    }
    __syncthreads();
  }
}

// merged Q/K/V projection GEMM; z selects input/weight/output+layout
__global__ __launch_bounds__(256, 3) void proj_gemm(
    const u16* __restrict__ Xq, const u16* __restrict__ Xk, const u16* __restrict__ Xv,
    const u16* __restrict__ Wqm, const u16* __restrict__ Wkm, const u16* __restrict__ Wvm,
    u16* __restrict__ Qp, u16* __restrict__ Kp, u16* __restrict__ VTp) {
  __shared__ u16 As[2][128 * 64];
  __shared__ u16 Bs[2][64 * 64];
  const int z = blockIdx.z;
  const u16* A  = (z == 0) ? Xq : (z == 1) ? Xk : Xv;
  const u16* Bw = (z == 0) ? Wqm : (z == 1) ? Wkm : Wvm;
  const int tid = threadIdx.x;
  const int m0 = blockIdx.y * 128, n0 = blockIdx.x * 64;

  f32x4 acc[2][4];
#pragma unroll
  for (int mf = 0; mf < 2; ++mf)
#pragma unroll
    for (int ni = 0; ni < 4; ++ni) acc[mf][ni] = (f32x4){0.f, 0.f, 0.f, 0.f};

  gemm_core(A, Bw, m0, n0, tid, acc, &As[0][0], &Bs[0][0]);

  const int l = tid & 63, w = tid >> 6, g = l >> 4, r16 = l & 15;
#pragma unroll
  for (int mf = 0; mf < 2; ++mf)
#pragma unroll
    for (int ni = 0; ni < 4; ++ni)
#pragma unroll
      for (int r = 0; r < 4; ++r) {
        const int m = m0 + w * 32 + mf * 16 + 4 * g + r;
        const int n = n0 + ni * 16 + r16;
        const float v = acc[mf][ni][r];
        const int b = m >> 12, s = m & 4095;
        const int h = n >> 6, d = n & 63;
        if (z < 2) {
          u16* out = z ? Kp : Qp;
          out[((size_t)(b * NH + h) * S_LEN + s) * 64 + d] = f2bf(v);
        } else {
          VTp[((size_t)(b * NH + h) * 64 + d) * S_LEN + s] = f2bf(v);
        }
      }
}

__global__ __launch_bounds__(256, 3) void out_gemm(const u16* __restrict__ A,
                                                   const u16* __restrict__ Bw,
                                                   float* __restrict__ out) {
  __shared__ u16 As[2][128 * 64];
  __shared__ u16 Bs[2][64 * 64];
  const int tid = threadIdx.x;
  const int m0 = blockIdx.y * 128, n0 = blockIdx.x * 64;

  f32x4 acc[2][4];
#pragma unroll
  for (int mf = 0; mf < 2; ++mf)
#pragma unroll
    for (int ni = 0; ni < 4; ++ni) acc[mf][ni] = (f32x4){0.f, 0.f, 0.f, 0.f};

  gemm_core(A, Bw, m0, n0, tid, acc, &As[0][0], &Bs[0][0]);

  const int l = tid & 63, w = tid >> 6, g = l >> 4, r16 = l & 15;
#pragma unroll
  for (int mf = 0; mf < 2; ++mf)
#pragma unroll
    for (int ni = 0; ni < 4; ++ni)
#pragma unroll
      for (int r = 0; r < 4; ++r) {
        const int m = m0 + w * 32 + mf * 16 + 4 * g + r;
        const int n = n0 + ni * 16 + r16;
        out[(size_t)m * DM + n] = acc[mf][ni][r];
      }
}

// ---------- causal flash attention ----------
// QBLK=128 (4 waves x 32 q-rows), KVBLK=64, double-buffered K/V, 1 barrier/tile.
// Scores arrive in log2-domain (scale folded into Wq); softmax uses exp2.
// Row-sum computed by MFMA against a ones-vector (no shuffle tree).
__global__ __launch_bounds__(256, 3) void attn128(const u16* __restrict__ Qp,
                                                  const u16* __restrict__ Kp,
                                                  const u16* __restrict__ VTp,
                                                  u16* __restrict__ Aout) {
  __shared__ u16 Kl[2][64 * 64];
  __shared__ u16 Vl[2][64 * 64];
  __shared__ u16 Pl[4][32 * 64];

  const int tid = threadIdx.x, l = tid & 63, w = tid >> 6;
  const int g = l >> 4, r16 = l & 15;

  // work-balanced remap: blocks lid and lid+256 get qi and 31-qi (const total work)
  const int lid = blockIdx.y * 32 + blockIdx.x;
  const int pos = lid & 255, half = lid >> 8;
  const int bh = (pos >> 5) + half * 8;
  const int qi = half ? (31 - (pos & 31)) : (pos & 31);
  const int q0 = qi * 128;
  const int nt = 2 * qi + 2;

  const u16* Kbase = Kp + (size_t)bh * S_LEN * 64;
  const u16* Vbase = VTp + (size_t)bh * 64 * S_LEN;

  // Q fragments in registers (already scaled by 0.125*log2e via Wq)
  s16x8 aq[2][2];
#pragma unroll
  for (int m = 0; m < 2; ++m)
#pragma unroll
    for (int kk = 0; kk < 2; ++kk)
      aq[m][kk] = *(const s16x8*)(Qp + ((size_t)bh * S_LEN + q0 + w * 32 + m * 16 + r16) * 64 +
                                  kk * 32 + g * 8);

  f32x4 oacc[2][4];
  f32x4 lacc[2];
  float mrow[2][4];
#pragma unroll
  for (int m = 0; m < 2; ++m) {
    lacc[m] = (f32x4){0.f, 0.f, 0.f, 0.f};
#pragma unroll
    for (int ni = 0; ni < 4; ++ni) oacc[m][ni] = (f32x4){0.f, 0.f, 0.f, 0.f};
#pragma unroll
    for (int r = 0; r < 4; ++r) mrow[m][r] = -1e30f;
  }

  s16x8 ones;
#pragma unroll
  for (int i = 0; i < 8; ++i) ones[i] = (short)0x3F80;  // bf16 1.0

  auto stage = [&](int buf, int t) {
    const int kv0 = t * 64;
#pragma unroll
    for (int s = 0; s < 2; ++s) {
      const int idx = s * 256 + tid;
      const int r = idx >> 3;
      const int c = (idx & 7) ^ SWZ(r);
      gload16(Kbase + (size_t)(kv0 + r) * 64 + c * 8, &Kl[buf][(s * 4 + w) * 512]);
      gload16(Vbase + (size_t)r * S_LEN + kv0 + c * 8, &Vl[buf][(s * 4 + w) * 512]);
    }
  };

  stage(0, 0);
  __syncthreads();

  for (int t = 0; t < nt; ++t) {
    const int cur = t & 1;
    if (t + 1 < nt) stage(cur ^ 1, t + 1);  // prefetch next tile under this tile's compute

    const u16* Kb = Kl[cur];
    const u16* Vb = Vl[cur];
    u16* Pw = Pl[w];

    // ---- QK^T (log2-domain scores) ----
    f32x4 sv[2][4];
#pragma unroll
    for (int ci = 0; ci < 4; ++ci) {
      s16x8 b0 = lds_frag(Kb, ci * 16 + r16, g);
      s16x8 b1 = lds_frag(Kb, ci * 16 + r16, 4 + g);
#pragma unroll
      for (int m = 0; m < 2; ++m) {
        f32x4 tacc = (f32x4){0.f, 0.f, 0.f, 0.f};
        tacc = __builtin_amdgcn_mfma_f32_16x16x32_bf16(aq[m][0], b0, tacc, 0, 0, 0);
        tacc = __builtin_amdgcn_mfma_f32_16x16x32_bf16(aq[m][1], b1, tacc, 0, 0, 0);
        sv[m][ci] = tacc;
      }
    }

    // ---- causal mask (last two tiles only) ----
    if (t >= nt - 2) {
      const int kv0 = t * 64;
#pragma unroll
      for (int m = 0; m < 2; ++m)
#pragma unroll
        for (int ci = 0; ci < 4; ++ci)
#pragma unroll
          for (int r = 0; r < 4; ++r) {
            const int row = q0 + w * 32 + m * 16 + 4 * g + r;
            const int col = kv0 + ci * 16 + r16;
            if (col > row) sv[m][ci][r] = -1e30f;
          }
    }

    // ---- online softmax (max via DPP on VALU; sum via ones-MFMA below) ----
#pragma unroll
    for (int m = 0; m < 2; ++m) {
      float fac[4];
#pragma unroll
      for (int r = 0; r < 4; ++r) {
        float tm = fmaxf(fmaxf(sv[m][0][r], sv[m][1][r]), fmaxf(sv[m][2][r], sv[m][3][r]));
        tm = dppmax16(tm);
        const float mnew = fmaxf(mrow[m][r], tm);
        fac[r] = fexp2(mrow[m][r] - mnew);
        mrow[m][r] = mnew;
      }
#pragma unroll
      for (int ci = 0; ci < 4; ++ci)
#pragma unroll
        for (int r = 0; r < 4; ++r) {
          const float pv = fexp2(sv[m][ci][r] - mrow[m][r]);
          const int row = m * 16 + 4 * g + r;
          const int col = ci * 16 + r16;
          Pw[row * 64 + ((col >> 3) ^ SWZ(row)) * 8 + (col & 7)] = f2bf(pv);
        }
#pragma unroll
      for (int r = 0; r < 4; ++r) {
        lacc[m][r] *= fac[r];
#pragma unroll
        for (int ni = 0; ni < 4; ++ni) oacc[m][ni][r] *= fac[r];
      }
    }

    // ---- PV + row-sum via ones-MFMA ----
#pragma unroll
    for (int kk = 0; kk < 2; ++kk) {
      s16x8 pa0 = lds_frag(Pw, r16, kk * 4 + g);
      s16x8 pa1 = lds_frag(Pw, 16 + r16, kk * 4 + g);
      lacc[0] = __builtin_amdgcn_mfma_f32_16x16x32_bf16(pa0, ones, lacc[0], 0, 0, 0);
      lacc[1] = __builtin_amdgcn_mfma_f32_16x16x32_bf16(pa1, ones, lacc[1], 0, 0, 0);
#pragma unroll
      for (int ni = 0; ni < 4; ++ni) {
        s16x8 bv = lds_frag(Vb, ni * 16 + r16, kk * 4 + g);
        oacc[0][ni] = __builtin_amdgcn_mfma_f32_16x16x32_bf16(pa0, bv, oacc[0][ni], 0, 0, 0);
        oacc[1][ni] = __builtin_amdgcn_mfma_f32_16x16x32_bf16(pa1, bv, oacc[1][ni], 0, 0, 0);
      }
    }
    __syncthreads();
  }

  // ---- epilogue: normalize and store ----
  const int b = bh >> 3, h = bh & 7;
#pragma unroll
  for (int m = 0; m < 2; ++m) {
    float rn[4];
#pragma unroll
    for (int r = 0; r < 4; ++r) rn[r] = frcp(lacc[m][r]);
#pragma unroll
    for (int ni = 0; ni < 4; ++ni)
#pragma unroll
      for (int r = 0; r < 4; ++r) {
        const int s = q0 + w * 32 + m * 16 + 4 * g + r;
        const int d = ni * 16 + r16;
        Aout[((size_t)b * S_LEN + s) * DM + h * 64 + d] = f2bf(oacc[m][ni][r] * rn[r]);
      }
  }
}

// ---------- launch ----------
extern "C" void kernel_launch(void* const* d_in, const int* in_sizes, int n_in,
                              void* d_out, int out_size, void* d_ws, size_t ws_size,
                              hipStream_t stream) {
  const float* q  = (const float*)d_in[0];
  const float* k  = (const float*)d_in[1];
  const float* v  = (const float*)d_in[2];
  const float* wq = (const float*)d_in[3];
  const float* wk = (const float*)d_in[4];
  const float* wv = (const float*)d_in[5];
  const float* wo = (const float*)d_in[6];

  char* ws = (char*)d_ws;
  u16* Xq  = (u16*)(ws + 0);
  u16* Xk  = (u16*)(ws + 8388608);
  u16* Xv  = (u16*)(ws + 16777216);
  u16* Wq  = (u16*)(ws + 25165824);
  u16* Wk  = (u16*)(ws + 25690112);
  u16* Wv  = (u16*)(ws + 26214400);
  u16* Wo  = (u16*)(ws + 26738688);
  u16* Qp  = (u16*)(ws + 27262976);
  u16* Kp  = (u16*)(ws + 35651584);
  u16* VTp = (u16*)(ws + 44040192);
  u16* Att = (u16*)(ws + 52428800);

  cvt_qkv<<<dim3(4096, 3), dim3(256), 0, stream>>>(q, k, v, Xq, Xk, Xv);
  cvt_w<<<dim3(256, 4), dim3(256), 0, stream>>>(wq, wk, wv, wo, Wq, Wk, Wv, Wo);

  proj_gemm<<<dim3(8, 64, 3), dim3(256), 0, stream>>>(Xq, Xk, Xv, Wq, Wk, Wv, Qp, Kp, VTp);

  attn128<<<dim3(32, 16), dim3(256), 0, stream>>>(Qp, Kp, VTp, Att);

  out_gemm<<<dim3(8, 64), dim3(256), 0, stream>>>(Att, Wo, (float*)d_out);
}

// Round 5
// 246.682 us; speedup vs baseline: 1.7408x; 1.1079x over previous
//
#include <hip/hip_runtime.h>

using f32x4 = __attribute__((ext_vector_type(4))) float;
using s16x8 = __attribute__((ext_vector_type(8))) short;
using u16   = unsigned short;
using u32   = unsigned int;
using u16x4 = __attribute__((ext_vector_type(4))) unsigned short;

#define S_LEN 4096
#define NH 8
#define DM 512
#define MROWS 8192  // B*S

// XOR swizzle on 16B chunks within a [row][64]-bf16 tile
#define SWZ(r) ((((r) & 7)) ^ ((((r) >> 2) & 2)))

// ---------- helpers ----------
static __device__ __forceinline__ u16 f2bf(float f) {
  u32 x = __builtin_bit_cast(u32, f);
  return (u16)((x + 0x7FFFu + ((x >> 16) & 1u)) >> 16);
}

static __device__ __forceinline__ float fexp2(float x) {
#if __has_builtin(__builtin_amdgcn_exp2f)
  return __builtin_amdgcn_exp2f(x);
#else
  return exp2f(x);
#endif
}

static __device__ __forceinline__ float frcp(float x) {
#if __has_builtin(__builtin_amdgcn_rcpf)
  return __builtin_amdgcn_rcpf(x);
#else
  return 1.0f / x;
#endif
}

// max over the 16 lanes of a DPP row (VALU pipe, no LDS)
static __device__ __forceinline__ float dppmax16(float x) {
  int v;
  v = __builtin_amdgcn_update_dpp(0, __builtin_bit_cast(int, x), 0xB1, 0xF, 0xF, true);
  x = fmaxf(x, __builtin_bit_cast(float, v));
  v = __builtin_amdgcn_update_dpp(0, __builtin_bit_cast(int, x), 0x4E, 0xF, 0xF, true);
  x = fmaxf(x, __builtin_bit_cast(float, v));
  v = __builtin_amdgcn_update_dpp(0, __builtin_bit_cast(int, x), 0x141, 0xF, 0xF, true);
  x = fmaxf(x, __builtin_bit_cast(float, v));
  v = __builtin_amdgcn_update_dpp(0, __builtin_bit_cast(int, x), 0x140, 0xF, 0xF, true);
  x = fmaxf(x, __builtin_bit_cast(float, v));
  return x;
}

typedef __attribute__((address_space(3))) void lds_void_t;
typedef const __attribute__((address_space(1))) void gbl_void_t;

static __device__ __forceinline__ void gload16(const void* g, void* l) {
  __builtin_amdgcn_global_load_lds((gbl_void_t*)g, (lds_void_t*)l, 16, 0, 0);
}

// 16B MFMA fragment from swizzled [R][64]-bf16 LDS tile
static __device__ __forceinline__ s16x8 lds_frag(const u16* base, int row, int c) {
  return *(const s16x8*)(base + row * 64 + ((c ^ SWZ(row)) << 3));
}

// ---------- fp32 -> bf16 conversion (single launch) ----------
__global__ void cvt_all(const float* __restrict__ q, const float* __restrict__ k,
                        const float* __restrict__ v, const float* __restrict__ wq,
                        const float* __restrict__ wk, const float* __restrict__ wv,
                        const float* __restrict__ wo, u16* __restrict__ oq,
                        u16* __restrict__ ok, u16* __restrict__ ov, u16* __restrict__ Wq,
                        u16* __restrict__ Wk, u16* __restrict__ Wv, u16* __restrict__ Wo) {
  const int z = blockIdx.y;
  if (z < 3) {
    const float* in = (z == 0) ? q : (z == 1) ? k : v;
    u16* out = (z == 0) ? oq : (z == 1) ? ok : ov;
    const int i = blockIdx.x * 256 + threadIdx.x;
    float4 t = ((const float4*)in)[i];
    u16x4 o;
    o.x = f2bf(t.x); o.y = f2bf(t.y); o.z = f2bf(t.z); o.w = f2bf(t.w);
    ((u16x4*)out)[i] = o;
  } else {
    if (blockIdx.x >= 1024) return;
    const int which = blockIdx.x >> 8;
    const float* in = (which == 0) ? wq : (which == 1) ? wk : (which == 2) ? wv : wo;
    u16* out = (which == 0) ? Wq : (which == 1) ? Wk : (which == 2) ? Wv : Wo;
    // Wq carries softmax scale in log2 domain: (1/8)*log2(e)
    const float scale = (which == 0) ? 0.18033688011112042f : 1.0f;
    const int i = (blockIdx.x & 255) * 256 + threadIdx.x;
    float4 t = ((const float4*)in)[i];
    u16x4 o;
    o.x = f2bf(t.x * scale); o.y = f2bf(t.y * scale);
    o.z = f2bf(t.z * scale); o.w = f2bf(t.w * scale);
    ((u16x4*)out)[i] = o;
  }
}

// ---------- NT bf16 GEMM core: 128x128 tile, BK=64, double-buffered ----------
// 256 thr / 4 waves in 2x2; wave (wr,wc) owns the 64x64 quadrant.
// global_load_lds LDS dest is wave-uniform (HW: base + lane*16B).
static __device__ __forceinline__ void gemm_core(const u16* __restrict__ A,
                                                 const u16* __restrict__ Bw,
                                                 int m0, int n0, int tid,
                                                 f32x4 (&acc)[4][4], u16* As, u16* Bs) {
  const int l = tid & 63;
  const int g = l >> 4, r16 = l & 15;
  const int w = tid >> 6, wr = w >> 1, wc = w & 1;

  auto stage = [&](int buf, int kt) {
    const int k0 = kt * 64;
#pragma unroll
    for (int s = 0; s < 4; ++s) {
      const int idx = s * 256 + tid;          // lane-varying (source side only)
      const int r = idx >> 3;
      const int c = (idx & 7) ^ SWZ(r);
      // dest: wave-uniform base (s*4+w)*512 u16; HW adds lane*16B -> idx*8
      gload16(A + (size_t)(m0 + r) * DM + k0 + c * 8, As + buf * 8192 + (s * 4 + w) * 512);
      gload16(Bw + (size_t)(n0 + r) * DM + k0 + c * 8, Bs + buf * 8192 + (s * 4 + w) * 512);
    }
  };

  stage(0, 0);
  __syncthreads();
  for (int kt = 0; kt < 8; ++kt) {
    const int cur = kt & 1;
    if (kt < 7) stage(cur ^ 1, kt + 1);  // prefetch next K-tile before compute
    const u16* Ab = As + cur * 8192 + wr * 64 * 64;
    const u16* Bb = Bs + cur * 8192 + wc * 64 * 64;
#pragma unroll
    for (int kk = 0; kk < 2; ++kk) {
      s16x8 af[4], bf[4];
#pragma unroll
      for (int mi = 0; mi < 4; ++mi) af[mi] = lds_frag(Ab, mi * 16 + r16, kk * 4 + g);
#pragma unroll
      for (int ni = 0; ni < 4; ++ni) bf[ni] = lds_frag(Bb, ni * 16 + r16, kk * 4 + g);
#pragma unroll
      for (int mi = 0; mi < 4; ++mi)
#pragma unroll
        for (int ni = 0; ni < 4; ++ni)
          acc[mi][ni] = __builtin_amdgcn_mfma_f32_16x16x32_bf16(af[mi], bf[ni], acc[mi][ni], 0, 0, 0);
    }
    __syncthreads();
  }
}

// merged Q/K/V projection; z==2 (V) does LDS transpose epilogue for coalesced VT writes
__global__ __launch_bounds__(256, 2) void proj_gemm(
    const u16* __restrict__ Xq, const u16* __restrict__ Xk, const u16* __restrict__ Xv,
    const u16* __restrict__ Wqm, const u16* __restrict__ Wkm, const u16* __restrict__ Wvm,
    u16* __restrict__ Qp, u16* __restrict__ Kp, u16* __restrict__ VTp) {
  __shared__ u16 As[2][8192];
  __shared__ u16 Bs[2][8192];
  // XCD-chunked remap: 768 blocks, 96 per XCD; same-A groups (4 n-tiles) stay together
  const int bid = blockIdx.x;
  const int logical = (bid & 7) * 96 + (bid >> 3);
  const int z = logical >> 8;
  const int rr = logical & 255;
  const int by = rr >> 2, bx = rr & 3;
  const int m0 = by * 128, n0 = bx * 128;

  const u16* A  = (z == 0) ? Xq : (z == 1) ? Xk : Xv;
  const u16* Bw = (z == 0) ? Wqm : (z == 1) ? Wkm : Wvm;
  const int tid = threadIdx.x;

  f32x4 acc[4][4];
#pragma unroll
  for (int mi = 0; mi < 4; ++mi)
#pragma unroll
    for (int ni = 0; ni < 4; ++ni) acc[mi][ni] = (f32x4){0.f, 0.f, 0.f, 0.f};

  gemm_core(A, Bw, m0, n0, tid, acc, &As[0][0], &Bs[0][0]);

  const int l = tid & 63, w = tid >> 6, g = l >> 4, r16 = l & 15;
  const int wr = w >> 1, wc = w & 1;

  if (z < 2) {
    u16* out = z ? Kp : Qp;
#pragma unroll
    for (int mi = 0; mi < 4; ++mi)
#pragma unroll
      for (int ni = 0; ni < 4; ++ni) {
        const int n = n0 + wc * 64 + ni * 16 + r16;
        const int h = n >> 6, d = n & 63;
#pragma unroll
        for (int r = 0; r < 4; ++r) {
          const int m = m0 + wr * 64 + mi * 16 + 4 * g + r;
          const int b = m >> 12, s = m & 4095;
          out[((size_t)(b * NH + h) * S_LEN + s) * 64 + d] = f2bf(acc[mi][ni][r]);
        }
      }
  } else {
    // transpose 128x128 tile through LDS, then coalesced VT row stores
    u16* Tt = &As[0][0];  // 16384 u16 = exactly the 128x128 tile
#pragma unroll
    for (int mi = 0; mi < 4; ++mi)
#pragma unroll
      for (int ni = 0; ni < 4; ++ni) {
        const int n = wc * 64 + ni * 16 + r16;     // VT row (col of C tile)
        const int mb = wr * 64 + mi * 16 + 4 * g;  // C row base (4 consecutive)
        const int ad = n * 128 + (((mb >> 3) ^ (n & 15)) << 3) + (mb & 7);
        Tt[ad + 0] = f2bf(acc[mi][ni][0]);
        Tt[ad + 1] = f2bf(acc[mi][ni][1]);
        Tt[ad + 2] = f2bf(acc[mi][ni][2]);
        Tt[ad + 3] = f2bf(acc[mi][ni][3]);
      }
    __syncthreads();
    const int b0 = m0 >> 12;
    const int srow0 = m0 & 4095;
    const int h0 = bx * 2;
#pragma unroll
    for (int it = 0; it < 8; ++it) {
      const int n = it * 16 + (tid >> 4);
      const int mc = tid & 15;
      s16x8 vch = *(const s16x8*)&Tt[n * 128 + ((mc ^ (n & 15)) << 3)];
      u16* dst = VTp + ((size_t)(b0 * NH + h0 + (n >> 6)) * 64 + (n & 63)) * S_LEN +
                 srow0 + mc * 8;
      *(s16x8*)dst = vch;
    }
  }
}

__global__ __launch_bounds__(256, 2) void out_gemm(const u16* __restrict__ A,
                                                   const u16* __restrict__ Bw,
                                                   float* __restrict__ out) {
  __shared__ u16 As[2][8192];
  __shared__ u16 Bs[2][8192];
  const int bid = blockIdx.x;
  const int logical = (bid & 7) * 32 + (bid >> 3);
  const int by = logical >> 2, bx = logical & 3;
  const int m0 = by * 128, n0 = bx * 128;
  const int tid = threadIdx.x;

  f32x4 acc[4][4];
#pragma unroll
  for (int mi = 0; mi < 4; ++mi)
#pragma unroll
    for (int ni = 0; ni < 4; ++ni) acc[mi][ni] = (f32x4){0.f, 0.f, 0.f, 0.f};

  gemm_core(A, Bw, m0, n0, tid, acc, &As[0][0], &Bs[0][0]);

  const int l = tid & 63, w = tid >> 6, g = l >> 4, r16 = l & 15;
  const int wr = w >> 1, wc = w & 1;
#pragma unroll
  for (int mi = 0; mi < 4; ++mi)
#pragma unroll
    for (int ni = 0; ni < 4; ++ni)
#pragma unroll
      for (int r = 0; r < 4; ++r) {
        const int m = m0 + wr * 64 + mi * 16 + 4 * g + r;
        const int n = n0 + wc * 64 + ni * 16 + r16;
        out[(size_t)m * DM + n] = acc[mi][ni][r];
      }
}

// ---------- causal flash attention (R2-proven version, verbatim) ----------
// QBLK=128 (4 waves x 32 q-rows), KVBLK=64, double-buffered K/V.
// Scores in log2 domain (scale folded into Wq); softmax uses exp2.
// Row-sum via ones-MFMA; row-max via DPP.
__global__ __launch_bounds__(256, 3) void attn128(const u16* __restrict__ Qp,
                                                  const u16* __restrict__ Kp,
                                                  const u16* __restrict__ VTp,
                                                  u16* __restrict__ Aout) {
  __shared__ u16 Kl[2][64 * 64];
  __shared__ u16 Vl[2][64 * 64];
  __shared__ u16 Pl[4][32 * 64];

  const int tid = threadIdx.x, l = tid & 63, w = tid >> 6;
  const int g = l >> 4, r16 = l & 15;

  // work-balanced remap: blocks lid and lid+256 get qi and 31-qi (const total work)
  const int lid = blockIdx.y * 32 + blockIdx.x;
  const int pos = lid & 255, half = lid >> 8;
  const int bh = (pos >> 5) + half * 8;
  const int qi = half ? (31 - (pos & 31)) : (pos & 31);
  const int q0 = qi * 128;
  const int nt = 2 * qi + 2;

  const u16* Kbase = Kp + (size_t)bh * S_LEN * 64;
  const u16* Vbase = VTp + (size_t)bh * 64 * S_LEN;

  // Q fragments in registers (already scaled by 0.125*log2e via Wq)
  s16x8 aq[2][2];
#pragma unroll
  for (int m = 0; m < 2; ++m)
#pragma unroll
    for (int kk = 0; kk < 2; ++kk)
      aq[m][kk] = *(const s16x8*)(Qp + ((size_t)bh * S_LEN + q0 + w * 32 + m * 16 + r16) * 64 +
                                  kk * 32 + g * 8);

  f32x4 oacc[2][4];
  f32x4 lacc[2];
  float mrow[2][4];
#pragma unroll
  for (int m = 0; m < 2; ++m) {
    lacc[m] = (f32x4){0.f, 0.f, 0.f, 0.f};
#pragma unroll
    for (int ni = 0; ni < 4; ++ni) oacc[m][ni] = (f32x4){0.f, 0.f, 0.f, 0.f};
#pragma unroll
    for (int r = 0; r < 4; ++r) mrow[m][r] = -1e30f;
  }

  s16x8 ones;
#pragma unroll
  for (int i = 0; i < 8; ++i) ones[i] = (short)0x3F80;  // bf16 1.0

  auto stage = [&](int buf, int t) {
    const int kv0 = t * 64;
#pragma unroll
    for (int s = 0; s < 2; ++s) {
      const int idx = s * 256 + tid;
      const int r = idx >> 3;
      const int c = (idx & 7) ^ SWZ(r);
      gload16(Kbase + (size_t)(kv0 + r) * 64 + c * 8, &Kl[buf][(s * 4 + w) * 512]);
      gload16(Vbase + (size_t)r * S_LEN + kv0 + c * 8, &Vl[buf][(s * 4 + w) * 512]);
    }
  };

  stage(0, 0);
  __syncthreads();

  for (int t = 0; t < nt; ++t) {
    const int cur = t & 1;
    if (t + 1 < nt) stage(cur ^ 1, t + 1);  // prefetch next tile under this tile's compute

    const u16* Kb = Kl[cur];
    const u16* Vb = Vl[cur];
    u16* Pw = Pl[w];

    // ---- QK^T (log2-domain scores) ----
    f32x4 sv[2][4];
#pragma unroll
    for (int ci = 0; ci < 4; ++ci) {
      s16x8 b0 = lds_frag(Kb, ci * 16 + r16, g);
      s16x8 b1 = lds_frag(Kb, ci * 16 + r16, 4 + g);
#pragma unroll
      for (int m = 0; m < 2; ++m) {
        f32x4 tacc = (f32x4){0.f, 0.f, 0.f, 0.f};
        tacc = __builtin_amdgcn_mfma_f32_16x16x32_bf16(aq[m][0], b0, tacc, 0, 0, 0);
        tacc = __builtin_amdgcn_mfma_f32_16x16x32_bf16(aq[m][1], b1, tacc, 0, 0, 0);
        sv[m][ci] = tacc;
      }
    }

    // ---- causal mask (last two tiles only) ----
    if (t >= nt - 2) {
      const int kv0 = t * 64;
#pragma unroll
      for (int m = 0; m < 2; ++m)
#pragma unroll
        for (int ci = 0; ci < 4; ++ci)
#pragma unroll
          for (int r = 0; r < 4; ++r) {
            const int row = q0 + w * 32 + m * 16 + 4 * g + r;
            const int col = kv0 + ci * 16 + r16;
            if (col > row) sv[m][ci][r] = -1e30f;
          }
    }

    // ---- online softmax (max via DPP; sum via ones-MFMA below) ----
#pragma unroll
    for (int m = 0; m < 2; ++m) {
      float fac[4];
#pragma unroll
      for (int r = 0; r < 4; ++r) {
        float tm = fmaxf(fmaxf(sv[m][0][r], sv[m][1][r]), fmaxf(sv[m][2][r], sv[m][3][r]));
        tm = dppmax16(tm);
        const float mnew = fmaxf(mrow[m][r], tm);
        fac[r] = fexp2(mrow[m][r] - mnew);
        mrow[m][r] = mnew;
      }
#pragma unroll
      for (int ci = 0; ci < 4; ++ci)
#pragma unroll
        for (int r = 0; r < 4; ++r) {
          const float pv = fexp2(sv[m][ci][r] - mrow[m][r]);
          const int row = m * 16 + 4 * g + r;
          const int col = ci * 16 + r16;
          Pw[row * 64 + ((col >> 3) ^ SWZ(row)) * 8 + (col & 7)] = f2bf(pv);
        }
#pragma unroll
      for (int r = 0; r < 4; ++r) {
        lacc[m][r] *= fac[r];
#pragma unroll
        for (int ni = 0; ni < 4; ++ni) oacc[m][ni][r] *= fac[r];
      }
    }

    // ---- PV + row-sum via ones-MFMA ----
#pragma unroll
    for (int kk = 0; kk < 2; ++kk) {
      s16x8 pa0 = lds_frag(Pw, r16, kk * 4 + g);
      s16x8 pa1 = lds_frag(Pw, 16 + r16, kk * 4 + g);
      lacc[0] = __builtin_amdgcn_mfma_f32_16x16x32_bf16(pa0, ones, lacc[0], 0, 0, 0);
      lacc[1] = __builtin_amdgcn_mfma_f32_16x16x32_bf16(pa1, ones, lacc[1], 0, 0, 0);
#pragma unroll
      for (int ni = 0; ni < 4; ++ni) {
        s16x8 bv = lds_frag(Vb, ni * 16 + r16, kk * 4 + g);
        oacc[0][ni] = __builtin_amdgcn_mfma_f32_16x16x32_bf16(pa0, bv, oacc[0][ni], 0, 0, 0);
        oacc[1][ni] = __builtin_amdgcn_mfma_f32_16x16x32_bf16(pa1, bv, oacc[1][ni], 0, 0, 0);
      }
    }
    __syncthreads();
  }

  // ---- epilogue: normalize and store ----
  const int b = bh >> 3, h = bh & 7;
#pragma unroll
  for (int m = 0; m < 2; ++m) {
    float rn[4];
#pragma unroll
    for (int r = 0; r < 4; ++r) rn[r] = frcp(lacc[m][r]);
#pragma unroll
    for (int ni = 0; ni < 4; ++ni)
#pragma unroll
      for (int r = 0; r < 4; ++r) {
        const int s = q0 + w * 32 + m * 16 + 4 * g + r;
        const int d = ni * 16 + r16;
        Aout[((size_t)b * S_LEN + s) * DM + h * 64 + d] = f2bf(oacc[m][ni][r] * rn[r]);
      }
  }
}

// ---------- launch ----------
extern "C" void kernel_launch(void* const* d_in, const int* in_sizes, int n_in,
                              void* d_out, int out_size, void* d_ws, size_t ws_size,
                              hipStream_t stream) {
  const float* q  = (const float*)d_in[0];
  const float* k  = (const float*)d_in[1];
  const float* v  = (const float*)d_in[2];
  const float* wq = (const float*)d_in[3];
  const float* wk = (const float*)d_in[4];
  const float* wv = (const float*)d_in[5];
  const float* wo = (const float*)d_in[6];

  char* ws = (char*)d_ws;
  u16* Xq  = (u16*)(ws + 0);
  u16* Xk  = (u16*)(ws + 8388608);
  u16* Xv  = (u16*)(ws + 16777216);
  u16* Wq  = (u16*)(ws + 25165824);
  u16* Wk  = (u16*)(ws + 25690112);
  u16* Wv  = (u16*)(ws + 26214400);
  u16* Wo  = (u16*)(ws + 26738688);
  u16* Qp  = (u16*)(ws + 27262976);
  u16* Kp  = (u16*)(ws + 35651584);
  u16* VTp = (u16*)(ws + 44040192);
  u16* Att = (u16*)(ws + 52428800);

  cvt_all<<<dim3(4096, 4), dim3(256), 0, stream>>>(q, k, v, wq, wk, wv, wo,
                                                   Xq, Xk, Xv, Wq, Wk, Wv, Wo);

  proj_gemm<<<dim3(768), dim3(256), 0, stream>>>(Xq, Xk, Xv, Wq, Wk, Wv, Qp, Kp, VTp);

  attn128<<<dim3(32, 16), dim3(256), 0, stream>>>(Qp, Kp, VTp, Att);

  out_gemm<<<dim3(256), dim3(256), 0, stream>>>(Att, Wo, (float*)d_out);
}

// Round 7
// 242.806 us; speedup vs baseline: 1.7686x; 1.0160x over previous
//
#include <hip/hip_runtime.h>

using f32x4 = __attribute__((ext_vector_type(4))) float;
using s16x8 = __attribute__((ext_vector_type(8))) short;
using u16   = unsigned short;
using u32   = unsigned int;
using u16x4 = __attribute__((ext_vector_type(4))) unsigned short;

#define S_LEN 4096
#define NH 8
#define DM 512
#define MROWS 8192  // B*S

// XOR swizzle on 16B chunks within a [row][64]-bf16 tile
#define SWZ(r) ((((r) & 7)) ^ ((((r) >> 2) & 2)))

// ---------- helpers ----------
static __device__ __forceinline__ u16 f2bf(float f) {
  u32 x = __builtin_bit_cast(u32, f);
  return (u16)((x + 0x7FFFu + ((x >> 16) & 1u)) >> 16);
}

static __device__ __forceinline__ float fexp2(float x) {
#if __has_builtin(__builtin_amdgcn_exp2f)
  return __builtin_amdgcn_exp2f(x);
#else
  return exp2f(x);
#endif
}

static __device__ __forceinline__ float frcp(float x) {
#if __has_builtin(__builtin_amdgcn_rcpf)
  return __builtin_amdgcn_rcpf(x);
#else
  return 1.0f / x;
#endif
}

// max over the 16 lanes of a DPP row (VALU pipe, no LDS)
static __device__ __forceinline__ float dppmax16(float x) {
  int v;
  v = __builtin_amdgcn_update_dpp(0, __builtin_bit_cast(int, x), 0xB1, 0xF, 0xF, true);
  x = fmaxf(x, __builtin_bit_cast(float, v));
  v = __builtin_amdgcn_update_dpp(0, __builtin_bit_cast(int, x), 0x4E, 0xF, 0xF, true);
  x = fmaxf(x, __builtin_bit_cast(float, v));
  v = __builtin_amdgcn_update_dpp(0, __builtin_bit_cast(int, x), 0x141, 0xF, 0xF, true);
  x = fmaxf(x, __builtin_bit_cast(float, v));
  v = __builtin_amdgcn_update_dpp(0, __builtin_bit_cast(int, x), 0x140, 0xF, 0xF, true);
  x = fmaxf(x, __builtin_bit_cast(float, v));
  return x;
}

typedef __attribute__((address_space(3))) void lds_void_t;
typedef const __attribute__((address_space(1))) void gbl_void_t;

static __device__ __forceinline__ void gload16(const void* g, void* l) {
  __builtin_amdgcn_global_load_lds((gbl_void_t*)g, (lds_void_t*)l, 16, 0, 0);
}

// 16B MFMA fragment from swizzled [R][64]-bf16 LDS tile
static __device__ __forceinline__ s16x8 lds_frag(const u16* base, int row, int c) {
  return *(const s16x8*)(base + row * 64 + ((c ^ SWZ(row)) << 3));
}

// ---------- fp32 -> bf16 conversion (single launch) ----------
__global__ void cvt_all(const float* __restrict__ q, const float* __restrict__ k,
                        const float* __restrict__ v, const float* __restrict__ wq,
                        const float* __restrict__ wk, const float* __restrict__ wv,
                        const float* __restrict__ wo, u16* __restrict__ oq,
                        u16* __restrict__ ok, u16* __restrict__ ov, u16* __restrict__ Wq,
                        u16* __restrict__ Wk, u16* __restrict__ Wv, u16* __restrict__ Wo) {
  const int z = blockIdx.y;
  if (z < 3) {
    const float* in = (z == 0) ? q : (z == 1) ? k : v;
    u16* out = (z == 0) ? oq : (z == 1) ? ok : ov;
    const int i = blockIdx.x * 256 + threadIdx.x;
    float4 t = ((const float4*)in)[i];
    u16x4 o;
    o.x = f2bf(t.x); o.y = f2bf(t.y); o.z = f2bf(t.z); o.w = f2bf(t.w);
    ((u16x4*)out)[i] = o;
  } else {
    if (blockIdx.x >= 1024) return;
    const int which = blockIdx.x >> 8;
    const float* in = (which == 0) ? wq : (which == 1) ? wk : (which == 2) ? wv : wo;
    u16* out = (which == 0) ? Wq : (which == 1) ? Wk : (which == 2) ? Wv : Wo;
    // Wq carries softmax scale in log2 domain: (1/8)*log2(e)
    const float scale = (which == 0) ? 0.18033688011112042f : 1.0f;
    const int i = (blockIdx.x & 255) * 256 + threadIdx.x;
    float4 t = ((const float4*)in)[i];
    u16x4 o;
    o.x = f2bf(t.x * scale); o.y = f2bf(t.y * scale);
    o.z = f2bf(t.z * scale); o.w = f2bf(t.w * scale);
    ((u16x4*)out)[i] = o;
  }
}

// ---------- NT bf16 GEMM core: 128x128 tile, BK=64, double-buffered ----------
// 256 thr / 4 waves in 2x2; wave (wr,wc) owns the 64x64 quadrant.
// global_load_lds LDS dest is wave-uniform (HW: base + lane*16B).
static __device__ __forceinline__ void gemm_core(const u16* __restrict__ A,
                                                 const u16* __restrict__ Bw,
                                                 int m0, int n0, int tid,
                                                 f32x4 (&acc)[4][4], u16* As, u16* Bs) {
  const int l = tid & 63;
  const int g = l >> 4, r16 = l & 15;
  const int w = tid >> 6, wr = w >> 1, wc = w & 1;

  auto stage = [&](int buf, int kt) {
    const int k0 = kt * 64;
#pragma unroll
    for (int s = 0; s < 4; ++s) {
      const int idx = s * 256 + tid;          // lane-varying (source side only)
      const int r = idx >> 3;
      const int c = (idx & 7) ^ SWZ(r);
      // dest: wave-uniform base (s*4+w)*512 u16; HW adds lane*16B -> idx*8
      gload16(A + (size_t)(m0 + r) * DM + k0 + c * 8, As + buf * 8192 + (s * 4 + w) * 512);
      gload16(Bw + (size_t)(n0 + r) * DM + k0 + c * 8, Bs + buf * 8192 + (s * 4 + w) * 512);
    }
  };

  stage(0, 0);
  __syncthreads();
  for (int kt = 0; kt < 8; ++kt) {
    const int cur = kt & 1;
    if (kt < 7) stage(cur ^ 1, kt + 1);  // prefetch next K-tile before compute
    const u16* Ab = As + cur * 8192 + wr * 64 * 64;
    const u16* Bb = Bs + cur * 8192 + wc * 64 * 64;
#pragma unroll
    for (int kk = 0; kk < 2; ++kk) {
      s16x8 af[4], bf[4];
#pragma unroll
      for (int mi = 0; mi < 4; ++mi) af[mi] = lds_frag(Ab, mi * 16 + r16, kk * 4 + g);
#pragma unroll
      for (int ni = 0; ni < 4; ++ni) bf[ni] = lds_frag(Bb, ni * 16 + r16, kk * 4 + g);
#pragma unroll
      for (int mi = 0; mi < 4; ++mi)
#pragma unroll
        for (int ni = 0; ni < 4; ++ni)
          acc[mi][ni] = __builtin_amdgcn_mfma_f32_16x16x32_bf16(af[mi], bf[ni], acc[mi][ni], 0, 0, 0);
    }
    __syncthreads();
  }
}

// merged Q/K/V projection; z==2 (V) does LDS transpose epilogue for coalesced VT writes
__global__ __launch_bounds__(256, 2) void proj_gemm(
    const u16* __restrict__ Xq, const u16* __restrict__ Xk, const u16* __restrict__ Xv,
    const u16* __restrict__ Wqm, const u16* __restrict__ Wkm, const u16* __restrict__ Wvm,
    u16* __restrict__ Qp, u16* __restrict__ Kp, u16* __restrict__ VTp) {
  __shared__ u16 As[2][8192];
  __shared__ u16 Bs[2][8192];
  // XCD-chunked remap: 768 blocks, 96 per XCD; same-A groups (4 n-tiles) stay together
  const int bid = blockIdx.x;
  const int logical = (bid & 7) * 96 + (bid >> 3);
  const int z = logical >> 8;
  const int rr = logical & 255;
  const int by = rr >> 2, bx = rr & 3;
  const int m0 = by * 128, n0 = bx * 128;

  const u16* A  = (z == 0) ? Xq : (z == 1) ? Xk : Xv;
  const u16* Bw = (z == 0) ? Wqm : (z == 1) ? Wkm : Wvm;
  const int tid = threadIdx.x;

  f32x4 acc[4][4];
#pragma unroll
  for (int mi = 0; mi < 4; ++mi)
#pragma unroll
    for (int ni = 0; ni < 4; ++ni) acc[mi][ni] = (f32x4){0.f, 0.f, 0.f, 0.f};

  gemm_core(A, Bw, m0, n0, tid, acc, &As[0][0], &Bs[0][0]);

  const int l = tid & 63, w = tid >> 6, g = l >> 4, r16 = l & 15;
  const int wr = w >> 1, wc = w & 1;

  if (z < 2) {
    u16* out = z ? Kp : Qp;
#pragma unroll
    for (int mi = 0; mi < 4; ++mi)
#pragma unroll
      for (int ni = 0; ni < 4; ++ni) {
        const int n = n0 + wc * 64 + ni * 16 + r16;
        const int h = n >> 6, d = n & 63;
#pragma unroll
        for (int r = 0; r < 4; ++r) {
          const int m = m0 + wr * 64 + mi * 16 + 4 * g + r;
          const int b = m >> 12, s = m & 4095;
          out[((size_t)(b * NH + h) * S_LEN + s) * 64 + d] = f2bf(acc[mi][ni][r]);
        }
      }
  } else {
    // transpose 128x128 tile through LDS, then coalesced VT row stores
    u16* Tt = &As[0][0];  // 16384 u16 = exactly the 128x128 tile
#pragma unroll
    for (int mi = 0; mi < 4; ++mi)
#pragma unroll
      for (int ni = 0; ni < 4; ++ni) {
        const int n = wc * 64 + ni * 16 + r16;     // VT row (col of C tile)
        const int mb = wr * 64 + mi * 16 + 4 * g;  // C row base (4 consecutive)
        const int ad = n * 128 + (((mb >> 3) ^ (n & 15)) << 3) + (mb & 7);
        Tt[ad + 0] = f2bf(acc[mi][ni][0]);
        Tt[ad + 1] = f2bf(acc[mi][ni][1]);
        Tt[ad + 2] = f2bf(acc[mi][ni][2]);
        Tt[ad + 3] = f2bf(acc[mi][ni][3]);
      }
    __syncthreads();
    const int b0 = m0 >> 12;
    const int srow0 = m0 & 4095;
    const int h0 = bx * 2;
#pragma unroll
    for (int it = 0; it < 8; ++it) {
      const int n = it * 16 + (tid >> 4);
      const int mc = tid & 15;
      s16x8 vch = *(const s16x8*)&Tt[n * 128 + ((mc ^ (n & 15)) << 3)];
      u16* dst = VTp + ((size_t)(b0 * NH + h0 + (n >> 6)) * 64 + (n & 63)) * S_LEN +
                 srow0 + mc * 8;
      *(s16x8*)dst = vch;
    }
  }
}

__global__ __launch_bounds__(256, 2) void out_gemm(const u16* __restrict__ A,
                                                   const u16* __restrict__ Bw,
                                                   float* __restrict__ out) {
  __shared__ u16 As[2][8192];
  __shared__ u16 Bs[2][8192];
  const int bid = blockIdx.x;
  const int logical = (bid & 7) * 32 + (bid >> 3);
  const int by = logical >> 2, bx = logical & 3;
  const int m0 = by * 128, n0 = bx * 128;
  const int tid = threadIdx.x;

  f32x4 acc[4][4];
#pragma unroll
  for (int mi = 0; mi < 4; ++mi)
#pragma unroll
    for (int ni = 0; ni < 4; ++ni) acc[mi][ni] = (f32x4){0.f, 0.f, 0.f, 0.f};

  gemm_core(A, Bw, m0, n0, tid, acc, &As[0][0], &Bs[0][0]);

  const int l = tid & 63, w = tid >> 6, g = l >> 4, r16 = l & 15;
  const int wr = w >> 1, wc = w & 1;
#pragma unroll
  for (int mi = 0; mi < 4; ++mi)
#pragma unroll
    for (int ni = 0; ni < 4; ++ni)
#pragma unroll
      for (int r = 0; r < 4; ++r) {
        const int m = m0 + wr * 64 + mi * 16 + 4 * g + r;
        const int n = n0 + wc * 64 + ni * 16 + r16;
        out[(size_t)m * DM + n] = acc[mi][ni][r];
      }
}

// ---------- causal flash attention ----------
// QBLK=64 (2 waves x 32 q-rows), KVBLK=64, double-buffered K/V.
// 1024 blocks -> 4 blocks/CU (LDS 40KB); longest blocks (high qi) dispatch first.
// Per-wave inner structure identical to the R2/R5-proven kernel.
// Scores in log2 domain (scale folded into Wq); row-sum via ones-MFMA; max via DPP.
__global__ __launch_bounds__(128, 2) void attn64(const u16* __restrict__ Qp,
                                                 const u16* __restrict__ Kp,
                                                 const u16* __restrict__ VTp,
                                                 u16* __restrict__ Aout) {
  __shared__ u16 Kl[2][64 * 64];
  __shared__ u16 Vl[2][64 * 64];
  __shared__ u16 Pl[2][32 * 64];

  const int tid = threadIdx.x, l = tid & 63, w = tid >> 6;  // w in {0,1}
  const int g = l >> 4, r16 = l & 15;

  // remap: XCD c hosts heads {2c, 2c+1}; qi descending with bid (longest first)
  const int bid = blockIdx.x;           // 0..1023
  const int c = bid & 7;                // XCD
  const int rr = bid >> 3;              // 0..127
  const int bh = 2 * c + (rr & 1);      // 0..15
  const int qi = 63 - (rr >> 1);        // 63..0
  const int q0 = qi * 64;
  const int nt = qi + 1;

  const u16* Kbase = Kp + (size_t)bh * S_LEN * 64;
  const u16* Vbase = VTp + (size_t)bh * 64 * S_LEN;

  // Q fragments in registers (already scaled by 0.125*log2e via Wq)
  s16x8 aq[2][2];
#pragma unroll
  for (int m = 0; m < 2; ++m)
#pragma unroll
    for (int kk = 0; kk < 2; ++kk)
      aq[m][kk] = *(const s16x8*)(Qp + ((size_t)bh * S_LEN + q0 + w * 32 + m * 16 + r16) * 64 +
                                  kk * 32 + g * 8);

  f32x4 oacc[2][4];
  f32x4 lacc[2];
  float mrow[2][4];
#pragma unroll
  for (int m = 0; m < 2; ++m) {
    lacc[m] = (f32x4){0.f, 0.f, 0.f, 0.f};
#pragma unroll
    for (int ni = 0; ni < 4; ++ni) oacc[m][ni] = (f32x4){0.f, 0.f, 0.f, 0.f};
#pragma unroll
    for (int r = 0; r < 4; ++r) mrow[m][r] = -1e30f;
  }

  s16x8 ones;
#pragma unroll
  for (int i = 0; i < 8; ++i) ones[i] = (short)0x3F80;  // bf16 1.0

  // stage one 64x64 K tile + 64x64 V tile; 128 threads -> 4 chunks of 16 rows each
  auto stage = [&](int buf, int t) {
    const int kv0 = t * 64;
#pragma unroll
    for (int s = 0; s < 4; ++s) {
      const int idx = s * 128 + tid;
      const int r = idx >> 3;
      const int cc = (idx & 7) ^ SWZ(r);
      gload16(Kbase + (size_t)(kv0 + r) * 64 + cc * 8, &Kl[buf][(s * 2 + w) * 512]);
      gload16(Vbase + (size_t)r * S_LEN + kv0 + cc * 8, &Vl[buf][(s * 2 + w) * 512]);
    }
  };

  stage(0, 0);
  __syncthreads();

  for (int t = 0; t < nt; ++t) {
    const int cur = t & 1;
    if (t + 1 < nt) stage(cur ^ 1, t + 1);  // prefetch next tile under this tile's compute

    const u16* Kb = Kl[cur];
    const u16* Vb = Vl[cur];
    u16* Pw = Pl[w];

    // ---- QK^T (log2-domain scores) ----
    f32x4 sv[2][4];
#pragma unroll
    for (int ci = 0; ci < 4; ++ci) {
      s16x8 b0 = lds_frag(Kb, ci * 16 + r16, g);
      s16x8 b1 = lds_frag(Kb, ci * 16 + r16, 4 + g);
#pragma unroll
      for (int m = 0; m < 2; ++m) {
        f32x4 tacc = (f32x4){0.f, 0.f, 0.f, 0.f};
        tacc = __builtin_amdgcn_mfma_f32_16x16x32_bf16(aq[m][0], b0, tacc, 0, 0, 0);
        tacc = __builtin_amdgcn_mfma_f32_16x16x32_bf16(aq[m][1], b1, tacc, 0, 0, 0);
        sv[m][ci] = tacc;
      }
    }

    // ---- causal mask (diagonal tile only: t == qi == nt-1) ----
    if (t == nt - 1) {
      const int kv0 = t * 64;
#pragma unroll
      for (int m = 0; m < 2; ++m)
#pragma unroll
        for (int ci = 0; ci < 4; ++ci)
#pragma unroll
          for (int r = 0; r < 4; ++r) {
            const int row = q0 + w * 32 + m * 16 + 4 * g + r;
            const int col = kv0 + ci * 16 + r16;
            if (col > row) sv[m][ci][r] = -1e30f;
          }
    }

    // ---- online softmax (max via DPP; sum via ones-MFMA below) ----
#pragma unroll
    for (int m = 0; m < 2; ++m) {
      float fac[4];
#pragma unroll
      for (int r = 0; r < 4; ++r) {
        float tm = fmaxf(fmaxf(sv[m][0][r], sv[m][1][r]), fmaxf(sv[m][2][r], sv[m][3][r]));
        tm = dppmax16(tm);
        const float mnew = fmaxf(mrow[m][r], tm);
        fac[r] = fexp2(mrow[m][r] - mnew);
        mrow[m][r] = mnew;
      }
#pragma unroll
      for (int ci = 0; ci < 4; ++ci)
#pragma unroll
        for (int r = 0; r < 4; ++r) {
          const float pv = fexp2(sv[m][ci][r] - mrow[m][r]);
          const int row = m * 16 + 4 * g + r;
          const int col = ci * 16 + r16;
          Pw[row * 64 + ((col >> 3) ^ SWZ(row)) * 8 + (col & 7)] = f2bf(pv);
        }
#pragma unroll
      for (int r = 0; r < 4; ++r) {
        lacc[m][r] *= fac[r];
#pragma unroll
        for (int ni = 0; ni < 4; ++ni) oacc[m][ni][r] *= fac[r];
      }
    }

    // ---- PV + row-sum via ones-MFMA ----
#pragma unroll
    for (int kk = 0; kk < 2; ++kk) {
      s16x8 pa0 = lds_frag(Pw, r16, kk * 4 + g);
      s16x8 pa1 = lds_frag(Pw, 16 + r16, kk * 4 + g);
      lacc[0] = __builtin_amdgcn_mfma_f32_16x16x32_bf16(pa0, ones, lacc[0], 0, 0, 0);
      lacc[1] = __builtin_amdgcn_mfma_f32_16x16x32_bf16(pa1, ones, lacc[1], 0, 0, 0);
#pragma unroll
      for (int ni = 0; ni < 4; ++ni) {
        s16x8 bv = lds_frag(Vb, ni * 16 + r16, kk * 4 + g);
        oacc[0][ni] = __builtin_amdgcn_mfma_f32_16x16x32_bf16(pa0, bv, oacc[0][ni], 0, 0, 0);
        oacc[1][ni] = __builtin_amdgcn_mfma_f32_16x16x32_bf16(pa1, bv, oacc[1][ni], 0, 0, 0);
      }
    }
    __syncthreads();
  }

  // ---- epilogue: normalize and store ----
  const int b = bh >> 3, h = bh & 7;
#pragma unroll
  for (int m = 0; m < 2; ++m) {
    float rn[4];
#pragma unroll
    for (int r = 0; r < 4; ++r) rn[r] = frcp(lacc[m][r]);
#pragma unroll
    for (int ni = 0; ni < 4; ++ni)
#pragma unroll
      for (int r = 0; r < 4; ++r) {
        const int s = q0 + w * 32 + m * 16 + 4 * g + r;
        const int d = ni * 16 + r16;
        Aout[((size_t)b * S_LEN + s) * DM + h * 64 + d] = f2bf(oacc[m][ni][r] * rn[r]);
      }
  }
}

// ---------- launch ----------
extern "C" void kernel_launch(void* const* d_in, const int* in_sizes, int n_in,
                              void* d_out, int out_size, void* d_ws, size_t ws_size,
                              hipStream_t stream) {
  const float* q  = (const float*)d_in[0];
  const float* k  = (const float*)d_in[1];
  const float* v  = (const float*)d_in[2];
  const float* wq = (const float*)d_in[3];
  const float* wk = (const float*)d_in[4];
  const float* wv = (const float*)d_in[5];
  const float* wo = (const float*)d_in[6];

  char* ws = (char*)d_ws;
  u16* Xq  = (u16*)(ws + 0);
  u16* Xk  = (u16*)(ws + 8388608);
  u16* Xv  = (u16*)(ws + 16777216);
  u16* Wq  = (u16*)(ws + 25165824);
  u16* Wk  = (u16*)(ws + 25690112);
  u16* Wv  = (u16*)(ws + 26214400);
  u16* Wo  = (u16*)(ws + 26738688);
  u16* Qp  = (u16*)(ws + 27262976);
  u16* Kp  = (u16*)(ws + 35651584);
  u16* VTp = (u16*)(ws + 44040192);
  u16* Att = (u16*)(ws + 52428800);

  cvt_all<<<dim3(4096, 4), dim3(256), 0, stream>>>(q, k, v, wq, wk, wv, wo,
                                                   Xq, Xk, Xv, Wq, Wk, Wv, Wo);

  proj_gemm<<<dim3(768), dim3(256), 0, stream>>>(Xq, Xk, Xv, Wq, Wk, Wv, Qp, Kp, VTp);

  attn64<<<dim3(1024), dim3(128), 0, stream>>>(Qp, Kp, VTp, Att);

  out_gemm<<<dim3(256), dim3(256), 0, stream>>>(Att, Wo, (float*)d_out);
}